// Round 3
// baseline (448.894 us; speedup 1.0000x reference)
//
#include <hip/hip_runtime.h>

// B=128, S=1024, H=256
#define Bb 128
#define Ss 1024
#define Hh 256
#define NEGF 1e9f

typedef short bf16x8 __attribute__((ext_vector_type(8)));
typedef float f32x4 __attribute__((ext_vector_type(4)));

__device__ __forceinline__ short f2bf(float f) {
    union { float f; unsigned u; } c; c.f = f;
    return (short)((c.u + 0x8000u) >> 16);
}

__device__ __forceinline__ float bfhi2f(unsigned u) {
    union { unsigned u; float f; } c; c.u = u & 0xFFFF0000u; return c.f;
}
__device__ __forceinline__ float bflo2f(unsigned u) {
    union { unsigned u; float f; } c; c.u = u << 16; return c.f;
}

__device__ __forceinline__ float fast_tanh(float x) {
    float cl = fminf(fmaxf(x, -10.f), 10.f);
    float e = __expf(2.f * cl);
    return (e - 1.f) * __builtin_amdgcn_rcpf(e + 1.f);
}

// ---------------- prep: wg,wp -> bf16 (blocks 0..255); qbias_g (blocks 256..383)
__global__ __launch_bounds__(256) void prep_kernel(const float* __restrict__ wg,
                                                   const float* __restrict__ wp,
                                                   const float* __restrict__ query,
                                                   const float* __restrict__ wqg,
                                                   const float* __restrict__ bg,
                                                   short* __restrict__ wgb,
                                                   short* __restrict__ wpb,
                                                   float* __restrict__ qbias_g) {
    int blk = blockIdx.x, t = threadIdx.x;
    if (blk < 256) {
        int i = blk * 256 + t;
        wgb[i] = f2bf(wg[i]);
        wpb[i] = f2bf(wp[i]);
    } else {
        int b = blk - 256;
        const float4* qr = (const float4*)(query + b * Hh);
        const float4* wr = (const float4*)(wqg + t * Hh);
        float acc = 0.f;
#pragma unroll 8
        for (int i = 0; i < Hh / 4; ++i) {
            float4 q4 = qr[i], w4 = wr[i];
            acc += q4.x * w4.x + q4.y * w4.y + q4.z * w4.z + q4.w * w4.w;
        }
        qbias_g[b * Hh + t] = acc + bg[t];
    }
}

// ---------------- Fused scores GEMM, W-in-registers + pipelined A stream.
// Grid = 512 blocks x 512 threads (8 waves), __launch_bounds__(512,2): 256-VGPR budget.
// Block owns 256 contiguous rows of one batch; wave w holds W n-slice [w*32,w*32+32)
// in registers (bfrag[2][8] = 64 VGPR, L2-resident load, once).
// Main loop: 16 tiles of 16 rows, explicit ping-pong A double-buffer (aA/aB, static
// indexing only): loads for tile t+1 are issued BEFORE tile t's MFMA+tanh block, so
// one full tile of compute (~400-500 cyc) x 2 waves/SIMD covers the (L3-resident)
// load latency. No LDS in the operand path, no barrier in the loop.
// LOADF32: A streams from fp32 ref, converted in-register; bf16 side-output written
// by wave w for tiles (tt&7)==w only (each tile stored exactly once per block).
template <int MASKED, int LOADF32>
__global__ __launch_bounds__(512, 2) void scores_mfma(const float* __restrict__ reff,
                                                      const short* __restrict__ refb_in,
                                                      short* __restrict__ refb_out,
                                                      const short* __restrict__ Wbf,
                                                      const float* __restrict__ qbias,
                                                      const float* __restrict__ vvec,
                                                      const int* __restrict__ mask,
                                                      float* __restrict__ out) {
    __shared__ float partial[8][256];
    const int t = threadIdx.x;
    const int w = t >> 6;
    const int lane = t & 63;
    const int nl = lane & 15;
    const int quad = lane >> 4;
    const int b = blockIdx.x >> 2;
    const int row0 = (blockIdx.x & 3) * 256;

    // persistent B fragments: lane (nl,quad) holds W[n = w*32+nc*16+nl][kb*32+quad*8 ..+8)
    bf16x8 bfrag[2][8];
#pragma unroll
    for (int nc = 0; nc < 2; ++nc) {
        const short* wp = Wbf + (w * 32 + nc * 16 + nl) * Hh + quad * 8;
#pragma unroll
        for (int kb = 0; kb < 8; ++kb)
            bfrag[nc][kb] = *(const bf16x8*)(wp + kb * 32);
    }
    const float qb0 = qbias[b * Hh + w * 32 + nl];
    const float qb1 = qbias[b * Hh + w * 32 + 16 + nl];
    const float vv0 = vvec[w * 32 + nl];
    const float vv1 = vvec[w * 32 + 16 + nl];

    // epilogue shared by both paths: MFMA chains + tanh + n-lane reduce
#define EPILOGUE(AF, TT)                                                               \
    {                                                                                  \
        f32x4 c0 = {0.f, 0.f, 0.f, 0.f};                                               \
        f32x4 c1 = {0.f, 0.f, 0.f, 0.f};                                               \
        _Pragma("unroll") for (int kb = 0; kb < 8; ++kb) {                             \
            c0 = __builtin_amdgcn_mfma_f32_16x16x32_bf16(AF[kb], bfrag[0][kb], c0, 0, 0, 0); \
            c1 = __builtin_amdgcn_mfma_f32_16x16x32_bf16(AF[kb], bfrag[1][kb], c1, 0, 0, 0); \
        }                                                                              \
        _Pragma("unroll") for (int r = 0; r < 4; ++r) {                                \
            float s = fast_tanh(c0[r] + qb0) * vv0 + fast_tanh(c1[r] + qb1) * vv1;     \
            s += __shfl_xor(s, 1, 64);                                                 \
            s += __shfl_xor(s, 2, 64);                                                 \
            s += __shfl_xor(s, 4, 64);                                                 \
            s += __shfl_xor(s, 8, 64);                                                 \
            if (nl == 0) partial[w][(TT) * 16 + quad * 4 + r] = s;                     \
        }                                                                              \
    }

    if (LOADF32) {
        const float* abase = reff + ((size_t)b * Ss + row0 + nl) * Hh + quad * 8;
        short* obase = refb_out + ((size_t)b * Ss + row0 + nl) * Hh + quad * 8;

#define LOADF(FB, TT)                                                                  \
    {                                                                                  \
        const float4* rp = (const float4*)(abase + (size_t)(TT) * 16 * Hh);            \
        _Pragma("unroll") for (int kb = 0; kb < 8; ++kb) {                             \
            FB[2 * kb]     = rp[kb * 8];                                               \
            FB[2 * kb + 1] = rp[kb * 8 + 1];                                           \
        }                                                                              \
    }
#define COMPF(FB, TT)                                                                  \
    {                                                                                  \
        bf16x8 af[8];                                                                  \
        _Pragma("unroll") for (int kb = 0; kb < 8; ++kb) {                             \
            float4 lo = FB[2 * kb], hi = FB[2 * kb + 1];                               \
            af[kb][0] = f2bf(lo.x); af[kb][1] = f2bf(lo.y);                            \
            af[kb][2] = f2bf(lo.z); af[kb][3] = f2bf(lo.w);                            \
            af[kb][4] = f2bf(hi.x); af[kb][5] = f2bf(hi.y);                            \
            af[kb][6] = f2bf(hi.z); af[kb][7] = f2bf(hi.w);                            \
        }                                                                              \
        if (((TT) & 7) == w) { /* this block's bf16 side-output, stored once */        \
            short* dst = obase + (size_t)(TT) * 16 * Hh;                               \
            _Pragma("unroll") for (int kb = 0; kb < 8; ++kb)                           \
                *(bf16x8*)(dst + kb * 32) = af[kb];                                    \
        }                                                                              \
        EPILOGUE(af, TT)                                                               \
    }

        float4 fA[16], fB[16];
        LOADF(fA, 0)
#pragma unroll 1
        for (int tt = 0; tt < 16; tt += 2) {
            LOADF(fB, tt + 1)
            COMPF(fA, tt)
            if (tt < 14) LOADF(fA, tt + 2)
            COMPF(fB, tt + 1)
        }
#undef LOADF
#undef COMPF
    } else {
        const short* abase = refb_in + ((size_t)b * Ss + row0 + nl) * Hh + quad * 8;

#define LOADB(AB, TT)                                                                  \
    {                                                                                  \
        const short* rp = abase + (size_t)(TT) * 16 * Hh;                              \
        _Pragma("unroll") for (int kb = 0; kb < 8; ++kb)                               \
            AB[kb] = *(const bf16x8*)(rp + kb * 32);                                   \
    }

        bf16x8 aA[8], aB[8];
        LOADB(aA, 0)
#pragma unroll 1
        for (int tt = 0; tt < 16; tt += 2) {
            LOADB(aB, tt + 1)
            EPILOGUE(aA, tt)
            if (tt < 14) LOADB(aA, tt + 2)
            EPILOGUE(aB, tt + 1)
        }
#undef LOADB
    }
#undef EPILOGUE

    __syncthreads();
    if (t < 256) {
        float s = 0.f;
#pragma unroll
        for (int g = 0; g < 8; ++g) s += partial[g][t];
        if (MASKED) s -= (float)mask[b * Ss + row0 + t] * NEGF;
        out[(size_t)b * Ss + row0 + t] = s;
    }
}

// ---------------- Softmax over S per batch (mask applied) -> att ----------------
__global__ __launch_bounds__(1024) void softmax_kernel(const float* __restrict__ scores,
                                                       const int* __restrict__ mask,
                                                       float* __restrict__ att) {
    int b = blockIdx.x, t = threadIdx.x;
    __shared__ float red[16];
    int idx = b * Ss + t;
    float x = scores[idx] - (float)mask[idx] * NEGF;

    float m = x;
#pragma unroll
    for (int o = 1; o < 64; o <<= 1) m = fmaxf(m, __shfl_xor(m, o, 64));
    if ((t & 63) == 0) red[t >> 6] = m;
    __syncthreads();
    float M = red[0];
#pragma unroll
    for (int j = 1; j < 16; ++j) M = fmaxf(M, red[j]);
    __syncthreads();

    float e = __expf(x - M);
    float s = e;
#pragma unroll
    for (int o = 1; o < 64; o <<= 1) s += __shfl_xor(s, o, 64);
    if ((t & 63) == 0) red[t >> 6] = s;
    __syncthreads();
    float S = 0.f;
#pragma unroll
    for (int j = 0; j < 16; ++j) S += red[j];

    att[idx] = e * __builtin_amdgcn_rcpf(S);
}

// ---------------- Glimpse partial (bf16 ref): gpart[b,q,d] = sum_{s in 1/8th q} att*ref
__global__ __launch_bounds__(256) void glimpse_part(const unsigned* __restrict__ refb,
                                                    const float* __restrict__ att,
                                                    float* __restrict__ gpart) {
    int b = blockIdx.x, q = blockIdx.y, t = threadIdx.x;
    const int c = t & 31;      // 16B chunk: d = c*8 .. c*8+7
    const int rg = t >> 5;     // row group 0..7
    __shared__ float part[8][Hh];
    const unsigned* base = refb + ((size_t)(b * Ss + q * 128)) * (Hh / 2);
    const float* ap = att + b * Ss + q * 128;

    float acc[8] = {0.f, 0.f, 0.f, 0.f, 0.f, 0.f, 0.f, 0.f};
#pragma unroll 4
    for (int it = 0; it < 16; ++it) {
        int row = it * 8 + rg;
        float a = ap[row];
        uint4 v = *(const uint4*)(base + (size_t)row * (Hh / 2) + c * 4);
        acc[0] += a * bflo2f(v.x); acc[1] += a * bfhi2f(v.x);
        acc[2] += a * bflo2f(v.y); acc[3] += a * bfhi2f(v.y);
        acc[4] += a * bflo2f(v.z); acc[5] += a * bfhi2f(v.z);
        acc[6] += a * bflo2f(v.w); acc[7] += a * bfhi2f(v.w);
    }
#pragma unroll
    for (int j = 0; j < 8; ++j) part[rg][c * 8 + j] = acc[j];
    __syncthreads();
    float s = 0.f;
#pragma unroll
    for (int g = 0; g < 8; ++g) s += part[g][t];
    gpart[(size_t)(b * 8 + q) * Hh + t] = s;
}

// ---------------- qbias_p[b,h] = sum_d glimpse[b,d]*wqp[h,d] + bp[h] ------------
__global__ __launch_bounds__(256) void qbias_p_kernel(const float* __restrict__ gpart,
                                                      const float* __restrict__ query,
                                                      const float* __restrict__ wqp,
                                                      const float* __restrict__ bp,
                                                      float* __restrict__ out) {
    int b = blockIdx.x, t = threadIdx.x;
    __shared__ __align__(16) float gl[Hh];
    float g = query[b * Hh + t];
#pragma unroll
    for (int q = 0; q < 8; ++q) g += gpart[(b * 8 + q) * Hh + t];
    gl[t] = g;
    __syncthreads();
    const float4* wr = (const float4*)(wqp + t * Hh);
    const float4* gp = (const float4*)gl;
    float acc = 0.f;
#pragma unroll 8
    for (int i = 0; i < Hh / 4; ++i) {
        float4 w4 = wr[i];
        float4 g4 = gp[i];
        acc += w4.x * g4.x + w4.y * g4.y + w4.z * g4.z + w4.w * g4.w;
    }
    out[b * Hh + t] = acc + bp[t];
}

extern "C" void kernel_launch(void* const* d_in, const int* in_sizes, int n_in,
                              void* d_out, int out_size, void* d_ws, size_t ws_size,
                              hipStream_t stream) {
    const float* ref   = (const float*)d_in[0];
    const float* query = (const float*)d_in[1];
    const int*   mask  = (const int*)d_in[2];
    const float* wg    = (const float*)d_in[3];
    const float* bg    = (const float*)d_in[4];
    const float* wqg   = (const float*)d_in[5];
    const float* vg    = (const float*)d_in[6];
    const float* wp    = (const float*)d_in[7];
    const float* bp    = (const float*)d_in[8];
    const float* wqp   = (const float*)d_in[9];
    const float* vp    = (const float*)d_in[10];
    float* out = (float*)d_out;

    char* ws = (char*)d_ws;
    short* ref_bf   = (short*)(ws + 0);          // 64 MB (B*S*H bf16)
    size_t off = (size_t)Bb * Ss * Hh * 2;
    short* wg_bf    = (short*)(ws + off);               off += 131072;
    short* wp_bf    = (short*)(ws + off);               off += 131072;
    float* qbias_g  = (float*)(ws + off);               off += 131072;
    float* qbias_p  = (float*)(ws + off);               off += 131072;
    float* scores_g = (float*)(ws + off);               off += 524288;
    float* att      = (float*)(ws + off);               off += 524288;
    float* gpart    = (float*)(ws + off);               // 1 MB

    prep_kernel<<<384, 256, 0, stream>>>(wg, wp, query, wqg, bg, wg_bf, wp_bf, qbias_g);
    // glimpse scores: fp32 ref in, bf16 side-output; unmasked (softmax applies mask)
    scores_mfma<0, 1><<<512, 512, 0, stream>>>(
        ref, nullptr, ref_bf, wg_bf, qbias_g, vg, nullptr, scores_g);
    softmax_kernel<<<Bb, Ss, 0, stream>>>(scores_g, mask, att);
    glimpse_part<<<dim3(Bb, 8), 256, 0, stream>>>((const unsigned*)ref_bf, att, gpart);
    qbias_p_kernel<<<Bb, Hh, 0, stream>>>(gpart, query, wqp, bp, qbias_p);
    // pointer scores: bf16 ref in, masked, straight to d_out
    scores_mfma<1, 0><<<512, 512, 0, stream>>>(
        nullptr, ref_bf, nullptr, wp_bf, qbias_p, vp, mask, out);
}

// Round 4
// 307.662 us; speedup vs baseline: 1.4590x; 1.4590x over previous
//
#include <hip/hip_runtime.h>

// B=128, S=1024, H=256
#define Bb 128
#define Ss 1024
#define Hh 256
#define NEGF 1e9f

typedef short bf16x8 __attribute__((ext_vector_type(8)));
typedef float f32x4 __attribute__((ext_vector_type(4)));

__device__ __forceinline__ short f2bf(float f) {
    union { float f; unsigned u; } c; c.f = f;
    return (short)((c.u + 0x8000u) >> 16);
}

__device__ __forceinline__ float bfhi2f(unsigned u) {
    union { unsigned u; float f; } c; c.u = u & 0xFFFF0000u; return c.f;
}
__device__ __forceinline__ float bflo2f(unsigned u) {
    union { unsigned u; float f; } c; c.u = u << 16; return c.f;
}

__device__ __forceinline__ bf16x8 ld_bf8_f32(const float* p) {
    const float4* p4 = (const float4*)p;
    float4 a = p4[0], b = p4[1];
    bf16x8 r;
    r[0] = f2bf(a.x); r[1] = f2bf(a.y); r[2] = f2bf(a.z); r[3] = f2bf(a.w);
    r[4] = f2bf(b.x); r[5] = f2bf(b.y); r[6] = f2bf(b.z); r[7] = f2bf(b.w);
    return r;
}

__device__ __forceinline__ float fast_tanh(float x) {
    float cl = fminf(fmaxf(x, -10.f), 10.f);
    float e = __expf(2.f * cl);
    return (e - 1.f) * __builtin_amdgcn_rcpf(e + 1.f);
}

// async global->LDS, 16B per lane; dest = (wave-uniform) lds base + lane*16
__device__ __forceinline__ void stage16(const short* g, short* l) {
    __builtin_amdgcn_global_load_lds((const __attribute__((address_space(1))) void*)g,
                                     (__attribute__((address_space(3))) void*)l, 16, 0, 0);
}

// ---------------- prep: wg,wp -> bf16 (blocks 0..255); qbias_g (blocks 256..383)
__global__ __launch_bounds__(256) void prep_kernel(const float* __restrict__ wg,
                                                   const float* __restrict__ wp,
                                                   const float* __restrict__ query,
                                                   const float* __restrict__ wqg,
                                                   const float* __restrict__ bg,
                                                   short* __restrict__ wgb,
                                                   short* __restrict__ wpb,
                                                   float* __restrict__ qbias_g) {
    int blk = blockIdx.x, t = threadIdx.x;
    if (blk < 256) {
        int i = blk * 256 + t;
        wgb[i] = f2bf(wg[i]);
        wpb[i] = f2bf(wp[i]);
    } else {
        int b = blk - 256;
        const float4* qr = (const float4*)(query + b * Hh);
        const float4* wr = (const float4*)(wqg + t * Hh);
        float acc = 0.f;
#pragma unroll 8
        for (int i = 0; i < Hh / 4; ++i) {
            float4 q4 = qr[i], w4 = wr[i];
            acc += q4.x * w4.x + q4.y * w4.y + q4.z * w4.z + q4.w * w4.w;
        }
        qbias_g[b * Hh + t] = acc + bg[t];
    }
}

// ---------------- Fused scores GEMM v4: full-W-in-LDS, one barrier, wave-private rows.
// Grid = 256 blocks x 512 threads (8 waves), 1 block/CU (128 KB LDS).
// Stage all of W once (wave w stages n-chunks 2w, 2w+1 via global_load_lds; layout
// [nc(16)][kb(8)][quad(4)][nl(16)][8] shorts — verified in r1). ONE __syncthreads.
// Each wave owns 64 rows (4 row-tiles of 16): afrag[4][8] = 128 VGPR, loaded straight
// from global (converted from fp32 in pass 1, with bf16 side-output; bf16 in pass 2).
// nc-loop (16 iters): 8 ds_read_b128 -> bfrag, reused by 4 MFMA chains (4x B-reuse
// keeps LDS pipe at ~half the MFMA pipe), tanh()*v accumulated into sc[4][4] across
// nc; single shfl-reduce over the 16 n-lanes at the end; rows written exclusively
// per wave (no cross-wave combine, no LDS partials, no end barrier).
template <int MASKED, int LOADF32>
__global__ __launch_bounds__(512, 1) void scores_mfma(const float* __restrict__ reff,
                                                      const short* __restrict__ refb_in,
                                                      short* __restrict__ refb_out,
                                                      const short* __restrict__ Wbf,
                                                      const float* __restrict__ qbias,
                                                      const float* __restrict__ vvec,
                                                      const int* __restrict__ mask,
                                                      float* __restrict__ out) {
    __shared__ __align__(16) short Wlds[65536];  // 128 KB
    const int t = threadIdx.x;
    const int w = t >> 6;
    const int lane = t & 63;
    const int nl = lane & 15;
    const int quad = lane >> 4;
    const int b = blockIdx.x >> 1;
    const int row0 = (blockIdx.x & 1) * 512 + w * 64;  // wave's 64 rows within batch b

    // ---- stage full W (wave w: nc = 2w, 2w+1; 16 x 1KB async copies) ----
#pragma unroll
    for (int h = 0; h < 2; ++h) {
        const int nc = w * 2 + h;
        const short* g = Wbf + (nc * 16 + nl) * Hh + quad * 8;
        short* l = &Wlds[nc * 4096];
#pragma unroll
        for (int kb = 0; kb < 8; ++kb)
            stage16(g + kb * 32, l + kb * 512);
    }

    // ---- A fragments: 4 row-tiles, element j at k = kb*32 + quad*8 + j ----
    const size_t arow = (size_t)b * Ss + row0 + nl;
    bf16x8 afrag[4][8];
    if (LOADF32) {
#pragma unroll
        for (int tile = 0; tile < 4; ++tile) {
            const float* rp = reff + (arow + tile * 16) * Hh + quad * 8;
            short* dst = refb_out + (arow + tile * 16) * Hh + quad * 8;
#pragma unroll
            for (int kb = 0; kb < 8; ++kb) {
                afrag[tile][kb] = ld_bf8_f32(rp + kb * 32);
                *(bf16x8*)(dst + kb * 32) = afrag[tile][kb];
            }
        }
    } else {
#pragma unroll
        for (int tile = 0; tile < 4; ++tile) {
            const short* rp = refb_in + (arow + tile * 16) * Hh + quad * 8;
#pragma unroll
            for (int kb = 0; kb < 8; ++kb)
                afrag[tile][kb] = *(const bf16x8*)(rp + kb * 32);
        }
    }

    __syncthreads();  // drains W staging (and A loads); ONLY barrier in the kernel

    const float* qb_row = qbias + b * Hh;
    float sc[4][4] = {{0.f, 0.f, 0.f, 0.f}, {0.f, 0.f, 0.f, 0.f},
                      {0.f, 0.f, 0.f, 0.f}, {0.f, 0.f, 0.f, 0.f}};

#pragma unroll 1
    for (int nc = 0; nc < 16; ++nc) {
        const float qb = qb_row[nc * 16 + nl];
        const float vv = vvec[nc * 16 + nl];
        bf16x8 bfrag[8];
#pragma unroll
        for (int kb = 0; kb < 8; ++kb)
            bfrag[kb] = *(const bf16x8*)&Wlds[nc * 4096 + kb * 512 + lane * 8];
#pragma unroll
        for (int tile = 0; tile < 4; ++tile) {
            f32x4 c = {0.f, 0.f, 0.f, 0.f};
#pragma unroll
            for (int kb = 0; kb < 8; ++kb)
                c = __builtin_amdgcn_mfma_f32_16x16x32_bf16(afrag[tile][kb], bfrag[kb], c, 0, 0, 0);
            // C/D: col = lane&15 (n-lane), row = quad*4 + r
#pragma unroll
            for (int r = 0; r < 4; ++r)
                sc[tile][r] += fast_tanh(c[r] + qb) * vv;
        }
    }

    // reduce over the 16 n-lanes within each quad; rows are wave-exclusive -> direct write
#pragma unroll
    for (int tile = 0; tile < 4; ++tile)
#pragma unroll
        for (int r = 0; r < 4; ++r) {
            float v = sc[tile][r];
            v += __shfl_xor(v, 1, 64);
            v += __shfl_xor(v, 2, 64);
            v += __shfl_xor(v, 4, 64);
            v += __shfl_xor(v, 8, 64);
            if (nl == 0) {
                int m = row0 + tile * 16 + quad * 4 + r;
                if (MASKED) v -= (float)mask[b * Ss + m] * NEGF;
                out[(size_t)b * Ss + m] = v;
            }
        }
}

// ---------------- Softmax over S per batch (mask applied) -> att ----------------
__global__ __launch_bounds__(1024) void softmax_kernel(const float* __restrict__ scores,
                                                       const int* __restrict__ mask,
                                                       float* __restrict__ att) {
    int b = blockIdx.x, t = threadIdx.x;
    __shared__ float red[16];
    int idx = b * Ss + t;
    float x = scores[idx] - (float)mask[idx] * NEGF;

    float m = x;
#pragma unroll
    for (int o = 1; o < 64; o <<= 1) m = fmaxf(m, __shfl_xor(m, o, 64));
    if ((t & 63) == 0) red[t >> 6] = m;
    __syncthreads();
    float M = red[0];
#pragma unroll
    for (int j = 1; j < 16; ++j) M = fmaxf(M, red[j]);
    __syncthreads();

    float e = __expf(x - M);
    float s = e;
#pragma unroll
    for (int o = 1; o < 64; o <<= 1) s += __shfl_xor(s, o, 64);
    if ((t & 63) == 0) red[t >> 6] = s;
    __syncthreads();
    float S = 0.f;
#pragma unroll
    for (int j = 0; j < 16; ++j) S += red[j];

    att[idx] = e * __builtin_amdgcn_rcpf(S);
}

// ---------------- Glimpse partial (bf16 ref): gpart[b,q,d] = sum_{s in 1/8th q} att*ref
__global__ __launch_bounds__(256) void glimpse_part(const unsigned* __restrict__ refb,
                                                    const float* __restrict__ att,
                                                    float* __restrict__ gpart) {
    int b = blockIdx.x, q = blockIdx.y, t = threadIdx.x;
    const int c = t & 31;      // 16B chunk: d = c*8 .. c*8+7
    const int rg = t >> 5;     // row group 0..7
    __shared__ float part[8][Hh];
    const unsigned* base = refb + ((size_t)(b * Ss + q * 128)) * (Hh / 2);
    const float* ap = att + b * Ss + q * 128;

    float acc[8] = {0.f, 0.f, 0.f, 0.f, 0.f, 0.f, 0.f, 0.f};
#pragma unroll 4
    for (int it = 0; it < 16; ++it) {
        int row = it * 8 + rg;
        float a = ap[row];
        uint4 v = *(const uint4*)(base + (size_t)row * (Hh / 2) + c * 4);
        acc[0] += a * bflo2f(v.x); acc[1] += a * bfhi2f(v.x);
        acc[2] += a * bflo2f(v.y); acc[3] += a * bfhi2f(v.y);
        acc[4] += a * bflo2f(v.z); acc[5] += a * bfhi2f(v.z);
        acc[6] += a * bflo2f(v.w); acc[7] += a * bfhi2f(v.w);
    }
#pragma unroll
    for (int j = 0; j < 8; ++j) part[rg][c * 8 + j] = acc[j];
    __syncthreads();
    float s = 0.f;
#pragma unroll
    for (int g = 0; g < 8; ++g) s += part[g][t];
    gpart[(size_t)(b * 8 + q) * Hh + t] = s;
}

// ---------------- qbias_p[b,h] = sum_d glimpse[b,d]*wqp[h,d] + bp[h] ------------
__global__ __launch_bounds__(256) void qbias_p_kernel(const float* __restrict__ gpart,
                                                      const float* __restrict__ query,
                                                      const float* __restrict__ wqp,
                                                      const float* __restrict__ bp,
                                                      float* __restrict__ out) {
    int b = blockIdx.x, t = threadIdx.x;
    __shared__ __align__(16) float gl[Hh];
    float g = query[b * Hh + t];
#pragma unroll
    for (int q = 0; q < 8; ++q) g += gpart[(b * 8 + q) * Hh + t];
    gl[t] = g;
    __syncthreads();
    const float4* wr = (const float4*)(wqp + t * Hh);
    const float4* gp = (const float4*)gl;
    float acc = 0.f;
#pragma unroll 8
    for (int i = 0; i < Hh / 4; ++i) {
        float4 w4 = wr[i];
        float4 g4 = gp[i];
        acc += w4.x * g4.x + w4.y * g4.y + w4.z * g4.z + w4.w * g4.w;
    }
    out[b * Hh + t] = acc + bp[t];
}

extern "C" void kernel_launch(void* const* d_in, const int* in_sizes, int n_in,
                              void* d_out, int out_size, void* d_ws, size_t ws_size,
                              hipStream_t stream) {
    const float* ref   = (const float*)d_in[0];
    const float* query = (const float*)d_in[1];
    const int*   mask  = (const int*)d_in[2];
    const float* wg    = (const float*)d_in[3];
    const float* bg    = (const float*)d_in[4];
    const float* wqg   = (const float*)d_in[5];
    const float* vg    = (const float*)d_in[6];
    const float* wp    = (const float*)d_in[7];
    const float* bp    = (const float*)d_in[8];
    const float* wqp   = (const float*)d_in[9];
    const float* vp    = (const float*)d_in[10];
    float* out = (float*)d_out;

    char* ws = (char*)d_ws;
    short* ref_bf   = (short*)(ws + 0);          // 64 MB (B*S*H bf16)
    size_t off = (size_t)Bb * Ss * Hh * 2;
    short* wg_bf    = (short*)(ws + off);               off += 131072;
    short* wp_bf    = (short*)(ws + off);               off += 131072;
    float* qbias_g  = (float*)(ws + off);               off += 131072;
    float* qbias_p  = (float*)(ws + off);               off += 131072;
    float* scores_g = (float*)(ws + off);               off += 524288;
    float* att      = (float*)(ws + off);               off += 524288;
    float* gpart    = (float*)(ws + off);               // 1 MB

    prep_kernel<<<384, 256, 0, stream>>>(wg, wp, query, wqg, bg, wg_bf, wp_bf, qbias_g);
    // glimpse scores: fp32 ref in, bf16 side-output; unmasked (softmax applies mask)
    scores_mfma<0, 1><<<256, 512, 0, stream>>>(
        ref, nullptr, ref_bf, wg_bf, qbias_g, vg, nullptr, scores_g);
    softmax_kernel<<<Bb, Ss, 0, stream>>>(scores_g, mask, att);
    glimpse_part<<<dim3(Bb, 8), 256, 0, stream>>>((const unsigned*)ref_bf, att, gpart);
    qbias_p_kernel<<<Bb, Hh, 0, stream>>>(gpart, query, wqp, bp, qbias_p);
    // pointer scores: bf16 ref in, masked, straight to d_out
    scores_mfma<1, 0><<<256, 512, 0, stream>>>(
        nullptr, ref_bf, nullptr, wp_bf, qbias_p, vp, mask, out);
}

// Round 5
// 293.278 us; speedup vs baseline: 1.5306x; 1.0490x over previous
//
#include <hip/hip_runtime.h>

// B=128, S=1024, H=256
#define Bb 128
#define Ss 1024
#define Hh 256
#define NEGF 1e9f

typedef short bf16x8 __attribute__((ext_vector_type(8)));
typedef float f32x4 __attribute__((ext_vector_type(4)));

__device__ __forceinline__ short f2bf(float f) {
    union { float f; unsigned u; } c; c.f = f;
    return (short)((c.u + 0x8000u) >> 16);
}

__device__ __forceinline__ float bfhi2f(unsigned u) {
    union { unsigned u; float f; } c; c.u = u & 0xFFFF0000u; return c.f;
}
__device__ __forceinline__ float bflo2f(unsigned u) {
    union { unsigned u; float f; } c; c.u = u << 16; return c.f;
}

__device__ __forceinline__ float fast_tanh(float x) {
    float cl = fminf(fmaxf(x, -10.f), 10.f);
    float e = __expf(2.f * cl);
    return (e - 1.f) * __builtin_amdgcn_rcpf(e + 1.f);
}

// async global->LDS, 16B per lane; dest = (wave-uniform) lds base + lane*16
__device__ __forceinline__ void stage16(const void* g, short* l) {
    __builtin_amdgcn_global_load_lds((const __attribute__((address_space(1))) void*)g,
                                     (__attribute__((address_space(3))) void*)l, 16, 0, 0);
}

// counted vmcnt wait: gfx9 encoding vm[3:0]|exp[6:4]|lgkm[11:8] (exp,lgkm = no-wait)
#define WAITVM(N) { __builtin_amdgcn_s_waitcnt(0x0F70 | (N)); __builtin_amdgcn_sched_barrier(0); }

// ---------------- prep: wg,wp -> bf16 (blocks 0..255); qbias_g (blocks 256..383)
__global__ __launch_bounds__(256) void prep_kernel(const float* __restrict__ wg,
                                                   const float* __restrict__ wp,
                                                   const float* __restrict__ query,
                                                   const float* __restrict__ wqg,
                                                   const float* __restrict__ bg,
                                                   short* __restrict__ wgb,
                                                   short* __restrict__ wpb,
                                                   float* __restrict__ qbias_g) {
    int blk = blockIdx.x, t = threadIdx.x;
    if (blk < 256) {
        int i = blk * 256 + t;
        wgb[i] = f2bf(wg[i]);
        wpb[i] = f2bf(wp[i]);
    } else {
        int b = blk - 256;
        const float4* qr = (const float4*)(query + b * Hh);
        const float4* wr = (const float4*)(wqg + t * Hh);
        float acc = 0.f;
#pragma unroll 8
        for (int i = 0; i < Hh / 4; ++i) {
            float4 q4 = qr[i], w4 = wr[i];
            acc += q4.x * w4.x + q4.y * w4.y + q4.z * w4.z + q4.w * w4.w;
        }
        qbias_g[b * Hh + t] = acc + bg[t];
    }
}

// ---------------- Fused scores GEMM v5: W-in-regs + A streamed via global_load_lds.
// Grid = 512 blocks x 512 threads (8 waves), 2 blocks/CU (40 KB LDS, VGPR<=128).
// Wave w holds W n-slice [w*32,w*32+32) in regs (bfrag[2][8]=64 VGPR, L2-hot load).
// Block owns 256 rows = 16 tiles of 16 rows. A tiles double-buffered in LDS in MFMA
// fragment order [kb][lane][16B] (linear per-lane ds_read_b128, conflict-free),
// staged by global_load_lds: per tile each wave issues I instr (pass1 fp32: I=2,
// pass2 bf16: I=1) -> >=32 KB/CU in flight, HBM-saturating, zero VGPR cost.
// Pipeline per tile: waitcnt vmcnt(I) (own loads, counted - NEVER drained to 0
// mid-loop) -> s_barrier -> ds_read+((convert+side-store))+16 MFMA+tanh+shfl ->
// s_barrier -> stage tile t+2 into freed buffer. (m201-verified protocol.)
// Partials: wave-exclusive LDS slots partial[8][256]; one final __syncthreads,
// then 256 threads sum 8 slices, apply mask, write (r2-verified combine).
template <int MASKED, int LOADF32>
__global__ __launch_bounds__(512, 2) void scores_mfma(const float* __restrict__ reff,
                                                      const short* __restrict__ refb_in,
                                                      short* __restrict__ refb_out,
                                                      const short* __restrict__ Wbf,
                                                      const float* __restrict__ qbias,
                                                      const float* __restrict__ vvec,
                                                      const int* __restrict__ mask,
                                                      float* __restrict__ out) {
    __shared__ __align__(16) short Abuf[2][8192];  // 2 x 16 KB (pass2 uses first 8 KB)
    __shared__ float partial[8][256];              // 8 KB
    const int t = threadIdx.x;
    const int w = t >> 6;
    const int lane = t & 63;
    const int nl = lane & 15;
    const int quad = lane >> 4;
    const int b = blockIdx.x >> 2;
    const int row0 = (blockIdx.x & 3) * 256;
    constexpr int I = LOADF32 ? 2 : 1;  // staging instructions per tile per wave

    // stage tile tt into Abuf[buf]: wave w supplies k-chunk kb=w.
    // source lane l -> ref[row0+tt*16+(l&15)][w*32+(l>>4)*8 (+half*4 fp32)]
    // dest: linear lane scatter -> LDS region [(w*2+half)*512] (fp32) / [w*512] (bf16)
    auto stage_tile = [&](int tt, int buf) {
        if (LOADF32) {
            const float* g = reff + ((size_t)b * Ss + row0 + tt * 16 + nl) * Hh + w * 32 + quad * 8;
            stage16(g,     &Abuf[buf][(w * 2 + 0) * 512]);
            stage16(g + 4, &Abuf[buf][(w * 2 + 1) * 512]);
        } else {
            const short* g = refb_in + ((size_t)b * Ss + row0 + tt * 16 + nl) * Hh + w * 32 + quad * 8;
            stage16(g, &Abuf[buf][w * 512]);
        }
    };

    stage_tile(0, 0);
    stage_tile(1, 1);

    // persistent W fragments: lane (nl,quad) holds W[w*32+nc2*16+nl][kb*32+quad*8 ..+8)
    bf16x8 bfrag[2][8];
#pragma unroll
    for (int nc2 = 0; nc2 < 2; ++nc2) {
        const short* wpr = Wbf + (w * 32 + nc2 * 16 + nl) * Hh + quad * 8;
#pragma unroll
        for (int kb = 0; kb < 8; ++kb)
            bfrag[nc2][kb] = *(const bf16x8*)(wpr + kb * 32);
    }
    const float qb0 = qbias[b * Hh + w * 32 + nl];
    const float qb1 = qbias[b * Hh + w * 32 + 16 + nl];
    const float vv0 = vvec[w * 32 + nl];
    const float vv1 = vvec[w * 32 + 16 + nl];

#pragma unroll 1
    for (int tt = 0; tt < 16; ++tt) {
        const int cur = tt & 1;
        // own stage loads for tile tt retired; tile tt+1's I loads stay in flight
        if (tt < 15) WAITVM(I) else WAITVM(0)
        __builtin_amdgcn_s_barrier();          // all waves' tile-tt data visible
        __builtin_amdgcn_sched_barrier(0);

        const short* bufp = Abuf[cur];
        short* dst = refb_out + ((size_t)b * Ss + row0 + tt * 16 + nl) * Hh + quad * 8;
        const bool sideout = LOADF32 && ((tt & 7) == w);

        f32x4 c0 = {0.f, 0.f, 0.f, 0.f};
        f32x4 c1 = {0.f, 0.f, 0.f, 0.f};
#pragma unroll
        for (int kb = 0; kb < 8; ++kb) {
            bf16x8 af;
            if (LOADF32) {
                float4 lo = *(const float4*)&bufp[(kb * 2 + 0) * 512 + lane * 8];
                float4 hi = *(const float4*)&bufp[(kb * 2 + 1) * 512 + lane * 8];
                af[0] = f2bf(lo.x); af[1] = f2bf(lo.y); af[2] = f2bf(lo.z); af[3] = f2bf(lo.w);
                af[4] = f2bf(hi.x); af[5] = f2bf(hi.y); af[6] = f2bf(hi.z); af[7] = f2bf(hi.w);
                if (sideout) *(bf16x8*)(dst + kb * 32) = af;   // bf16 ref side-output
            } else {
                af = *(const bf16x8*)&bufp[kb * 512 + lane * 8];
            }
            c0 = __builtin_amdgcn_mfma_f32_16x16x32_bf16(af, bfrag[0][kb], c0, 0, 0, 0);
            c1 = __builtin_amdgcn_mfma_f32_16x16x32_bf16(af, bfrag[1][kb], c1, 0, 0, 0);
        }
        // C/D: col = lane&15 (n-lane), row = quad*4 + r ; reduce over 16 n-lanes
#pragma unroll
        for (int r = 0; r < 4; ++r) {
            float s = fast_tanh(c0[r] + qb0) * vv0 + fast_tanh(c1[r] + qb1) * vv1;
            s += __shfl_xor(s, 1, 64);
            s += __shfl_xor(s, 2, 64);
            s += __shfl_xor(s, 4, 64);
            s += __shfl_xor(s, 8, 64);
            if (nl == 0) partial[w][tt * 16 + quad * 4 + r] = s;
        }

        __builtin_amdgcn_s_barrier();          // everyone done reading Abuf[cur]
        __builtin_amdgcn_sched_barrier(0);
        if (tt < 14) stage_tile(tt + 2, cur);  // refill freed buffer (stays in flight)
    }

    __syncthreads();
    if (t < 256) {
        float s = 0.f;
#pragma unroll
        for (int g = 0; g < 8; ++g) s += partial[g][t];
        if (MASKED) s -= (float)mask[b * Ss + row0 + t] * NEGF;
        out[(size_t)b * Ss + row0 + t] = s;
    }
}

// ---------------- Softmax over S per batch (mask applied) -> att ----------------
__global__ __launch_bounds__(1024) void softmax_kernel(const float* __restrict__ scores,
                                                       const int* __restrict__ mask,
                                                       float* __restrict__ att) {
    int b = blockIdx.x, t = threadIdx.x;
    __shared__ float red[16];
    int idx = b * Ss + t;
    float x = scores[idx] - (float)mask[idx] * NEGF;

    float m = x;
#pragma unroll
    for (int o = 1; o < 64; o <<= 1) m = fmaxf(m, __shfl_xor(m, o, 64));
    if ((t & 63) == 0) red[t >> 6] = m;
    __syncthreads();
    float M = red[0];
#pragma unroll
    for (int j = 1; j < 16; ++j) M = fmaxf(M, red[j]);
    __syncthreads();

    float e = __expf(x - M);
    float s = e;
#pragma unroll
    for (int o = 1; o < 64; o <<= 1) s += __shfl_xor(s, o, 64);
    if ((t & 63) == 0) red[t >> 6] = s;
    __syncthreads();
    float S = 0.f;
#pragma unroll
    for (int j = 0; j < 16; ++j) S += red[j];

    att[idx] = e * __builtin_amdgcn_rcpf(S);
}

// ---------------- Glimpse partial (bf16 ref): gpart[b,q,d] = sum_{s in 1/8th q} att*ref
__global__ __launch_bounds__(256) void glimpse_part(const unsigned* __restrict__ refb,
                                                    const float* __restrict__ att,
                                                    float* __restrict__ gpart) {
    int b = blockIdx.x, q = blockIdx.y, t = threadIdx.x;
    const int c = t & 31;      // 16B chunk: d = c*8 .. c*8+7
    const int rg = t >> 5;     // row group 0..7
    __shared__ float part[8][Hh];
    const unsigned* base = refb + ((size_t)(b * Ss + q * 128)) * (Hh / 2);
    const float* ap = att + b * Ss + q * 128;

    float acc[8] = {0.f, 0.f, 0.f, 0.f, 0.f, 0.f, 0.f, 0.f};
#pragma unroll 4
    for (int it = 0; it < 16; ++it) {
        int row = it * 8 + rg;
        float a = ap[row];
        uint4 v = *(const uint4*)(base + (size_t)row * (Hh / 2) + c * 4);
        acc[0] += a * bflo2f(v.x); acc[1] += a * bfhi2f(v.x);
        acc[2] += a * bflo2f(v.y); acc[3] += a * bfhi2f(v.y);
        acc[4] += a * bflo2f(v.z); acc[5] += a * bfhi2f(v.z);
        acc[6] += a * bflo2f(v.w); acc[7] += a * bfhi2f(v.w);
    }
#pragma unroll
    for (int j = 0; j < 8; ++j) part[rg][c * 8 + j] = acc[j];
    __syncthreads();
    float s = 0.f;
#pragma unroll
    for (int g = 0; g < 8; ++g) s += part[g][t];
    gpart[(size_t)(b * 8 + q) * Hh + t] = s;
}

// ---------------- qbias_p[b,h] = sum_d glimpse[b,d]*wqp[h,d] + bp[h] ------------
__global__ __launch_bounds__(256) void qbias_p_kernel(const float* __restrict__ gpart,
                                                      const float* __restrict__ query,
                                                      const float* __restrict__ wqp,
                                                      const float* __restrict__ bp,
                                                      float* __restrict__ out) {
    int b = blockIdx.x, t = threadIdx.x;
    __shared__ __align__(16) float gl[Hh];
    float g = query[b * Hh + t];
#pragma unroll
    for (int q = 0; q < 8; ++q) g += gpart[(b * 8 + q) * Hh + t];
    gl[t] = g;
    __syncthreads();
    const float4* wr = (const float4*)(wqp + t * Hh);
    const float4* gp = (const float4*)gl;
    float acc = 0.f;
#pragma unroll 8
    for (int i = 0; i < Hh / 4; ++i) {
        float4 w4 = wr[i];
        float4 g4 = gp[i];
        acc += w4.x * g4.x + w4.y * g4.y + w4.z * g4.z + w4.w * g4.w;
    }
    out[b * Hh + t] = acc + bp[t];
}

extern "C" void kernel_launch(void* const* d_in, const int* in_sizes, int n_in,
                              void* d_out, int out_size, void* d_ws, size_t ws_size,
                              hipStream_t stream) {
    const float* ref   = (const float*)d_in[0];
    const float* query = (const float*)d_in[1];
    const int*   mask  = (const int*)d_in[2];
    const float* wg    = (const float*)d_in[3];
    const float* bg    = (const float*)d_in[4];
    const float* wqg   = (const float*)d_in[5];
    const float* vg    = (const float*)d_in[6];
    const float* wp    = (const float*)d_in[7];
    const float* bp    = (const float*)d_in[8];
    const float* wqp   = (const float*)d_in[9];
    const float* vp    = (const float*)d_in[10];
    float* out = (float*)d_out;

    char* ws = (char*)d_ws;
    short* ref_bf   = (short*)(ws + 0);          // 64 MB (B*S*H bf16)
    size_t off = (size_t)Bb * Ss * Hh * 2;
    short* wg_bf    = (short*)(ws + off);               off += 131072;
    short* wp_bf    = (short*)(ws + off);               off += 131072;
    float* qbias_g  = (float*)(ws + off);               off += 131072;
    float* qbias_p  = (float*)(ws + off);               off += 131072;
    float* scores_g = (float*)(ws + off);               off += 524288;
    float* att      = (float*)(ws + off);               off += 524288;
    float* gpart    = (float*)(ws + off);               // 1 MB

    prep_kernel<<<384, 256, 0, stream>>>(wg, wp, query, wqg, bg, wg_bf, wp_bf, qbias_g);
    // glimpse scores: fp32 ref in, bf16 side-output; unmasked (softmax applies mask)
    scores_mfma<0, 1><<<512, 512, 0, stream>>>(
        ref, nullptr, ref_bf, wg_bf, qbias_g, vg, nullptr, scores_g);
    softmax_kernel<<<Bb, Ss, 0, stream>>>(scores_g, mask, att);
    glimpse_part<<<dim3(Bb, 8), 256, 0, stream>>>((const unsigned*)ref_bf, att, gpart);
    qbias_p_kernel<<<Bb, Hh, 0, stream>>>(gpart, query, wqp, bp, qbias_p);
    // pointer scores: bf16 ref in, masked, straight to d_out
    scores_mfma<1, 0><<<512, 512, 0, stream>>>(
        nullptr, ref_bf, nullptr, wp_bf, qbias_p, vp, mask, out);
}